// Round 1
// baseline (910.313 us; speedup 1.0000x reference)
//
#include <hip/hip_runtime.h>
#include <hip/hip_bf16.h>

// Problem constants (match reference)
#define NN   8192      // nodes
#define NE   524288    // edges
#define DH   16384     // 2N hidden
#define NOUT 32

// ---------------------------------------------------------------------------
// GCN stage kernels
// ---------------------------------------------------------------------------

__global__ __launch_bounds__(256) void k_deg_init(float* deg) {
    int i = blockIdx.x * blockDim.x + threadIdx.x;
    if (i < NN) deg[i] = 1.0f;   // self-loop contributes 1
}

__global__ __launch_bounds__(256) void k_deg_acc(const int* __restrict__ dst, float* deg) {
    int e = blockIdx.x * blockDim.x + threadIdx.x;
    if (e < NE) atomicAdd(&deg[dst[e]], 1.0f);
}

// dinv = rsqrt(deg) (in place); h1 = x0 @ W1.T ; zero agg1
__global__ __launch_bounds__(256) void k_dinv_h1(const float* __restrict__ x0,
                                                 const float* __restrict__ W1,
                                                 float* dinv, float* h1, float* agg1) {
    int i = blockIdx.x * blockDim.x + threadIdx.x;
    if (i >= NN) return;
    dinv[i] = rsqrtf(dinv[i]);           // deg >= 1 always (self-loop)
    float a = x0[2 * i], b = x0[2 * i + 1];
#pragma unroll
    for (int c = 0; c < 4; ++c) {
        h1[4 * i + c] = a * W1[2 * c] + b * W1[2 * c + 1];
        agg1[4 * i + c] = 0.0f;
    }
}

__global__ __launch_bounds__(256) void k_scat4(const int* __restrict__ src,
                                               const int* __restrict__ dst,
                                               const float* __restrict__ dinv,
                                               const float* __restrict__ h,
                                               float* agg) {
    int e = blockIdx.x * blockDim.x + threadIdx.x;
    if (e >= NE) return;
    int s = src[e], d = dst[e];
    float nrm = dinv[s] * dinv[d];
    float4 hv = *(const float4*)(h + 4 * s);
    atomicAdd(&agg[4 * d + 0], nrm * hv.x);
    atomicAdd(&agg[4 * d + 1], nrm * hv.y);
    atomicAdd(&agg[4 * d + 2], nrm * hv.z);
    atomicAdd(&agg[4 * d + 3], nrm * hv.w);
}

// x1 = relu(agg1 + dinv^2*h1 + b1); h2 = x1 @ W2.T ; zero agg2   (x1 never stored)
__global__ __launch_bounds__(256) void k_fin1_h2(const float* __restrict__ dinv,
                                                 const float* __restrict__ h1,
                                                 const float* __restrict__ agg1,
                                                 const float* __restrict__ b1,
                                                 const float* __restrict__ W2,
                                                 float* h2, float* agg2) {
    int i = blockIdx.x * blockDim.x + threadIdx.x;
    if (i >= NN) return;
    float di2 = dinv[i] * dinv[i];
    float x1[4];
#pragma unroll
    for (int c = 0; c < 4; ++c) {
        float t = agg1[4 * i + c] + di2 * h1[4 * i + c] + b1[c];
        x1[c] = fmaxf(t, 0.0f);
    }
#pragma unroll
    for (int c = 0; c < 2; ++c) {
        float t = 0.0f;
#pragma unroll
        for (int k = 0; k < 4; ++k) t += x1[k] * W2[4 * c + k];
        h2[2 * i + c] = t;
        agg2[2 * i + c] = 0.0f;
    }
}

__global__ __launch_bounds__(256) void k_scat2(const int* __restrict__ src,
                                               const int* __restrict__ dst,
                                               const float* __restrict__ dinv,
                                               const float* __restrict__ h,
                                               float* agg) {
    int e = blockIdx.x * blockDim.x + threadIdx.x;
    if (e >= NE) return;
    int s = src[e], d = dst[e];
    float nrm = dinv[s] * dinv[d];
    float2 hv = *(const float2*)(h + 2 * s);
    atomicAdd(&agg[2 * d + 0], nrm * hv.x);
    atomicAdd(&agg[2 * d + 1], nrm * hv.y);
}

// x2 = relu(agg2 + dinv^2*h2 + b2); h3 = x2 @ W3.T ; zero agg3
__global__ __launch_bounds__(256) void k_fin2_h3(const float* __restrict__ dinv,
                                                 const float* __restrict__ h2,
                                                 const float* __restrict__ agg2,
                                                 const float* __restrict__ b2,
                                                 const float* __restrict__ W3,
                                                 float* h3, float* agg3) {
    int i = blockIdx.x * blockDim.x + threadIdx.x;
    if (i >= NN) return;
    float di2 = dinv[i] * dinv[i];
    float x2a = fmaxf(agg2[2 * i + 0] + di2 * h2[2 * i + 0] + b2[0], 0.0f);
    float x2b = fmaxf(agg2[2 * i + 1] + di2 * h2[2 * i + 1] + b2[1], 0.0f);
    h3[i] = x2a * W3[0] + x2b * W3[1];
    agg3[i] = 0.0f;
}

__global__ __launch_bounds__(256) void k_scat1(const int* __restrict__ src,
                                               const int* __restrict__ dst,
                                               const float* __restrict__ dinv,
                                               const float* __restrict__ h,
                                               float* agg) {
    int e = blockIdx.x * blockDim.x + threadIdx.x;
    if (e >= NE) return;
    int s = src[e], d = dst[e];
    atomicAdd(&agg[d], dinv[s] * dinv[d] * h[s]);
}

__global__ __launch_bounds__(256) void k_fin3(const float* __restrict__ dinv,
                                              const float* __restrict__ h3,
                                              const float* __restrict__ agg3,
                                              const float* __restrict__ b3,
                                              float* v) {
    int i = blockIdx.x * blockDim.x + threadIdx.x;
    if (i >= NN) return;
    v[i] = agg3[i] + dinv[i] * dinv[i] * h3[i] + b3[0];
}

// ---------------------------------------------------------------------------
// Trailing MLP: y = tanh(v @ Wa.T + ba)  -- the 512 MB memory-bound matvec
// One row per block; 256 threads; float4 coalesced; wave shuffle + LDS reduce.
// ---------------------------------------------------------------------------

__global__ __launch_bounds__(256) void k_mv1(const float* __restrict__ v,
                                             const float* __restrict__ Wa,
                                             const float* __restrict__ ba,
                                             float* __restrict__ y) {
    __shared__ float sm[4];
    int j = blockIdx.x;
    const float4* wr = (const float4*)(Wa + (size_t)j * NN);
    const float4* vv = (const float4*)v;
    float acc = 0.0f;
#pragma unroll
    for (int it = 0; it < (NN / 4) / 256; ++it) {   // 8 iters
        int idx = it * 256 + threadIdx.x;
        float4 w = wr[idx];
        float4 x = vv[idx];
        acc += w.x * x.x + w.y * x.y + w.z * x.z + w.w * x.w;
    }
#pragma unroll
    for (int off = 32; off > 0; off >>= 1) acc += __shfl_down(acc, off, 64);
    int lane = threadIdx.x & 63, wid = threadIdx.x >> 6;
    if (lane == 0) sm[wid] = acc;
    __syncthreads();
    if (threadIdx.x == 0) y[j] = tanhf(sm[0] + sm[1] + sm[2] + sm[3] + ba[j]);
}

__global__ __launch_bounds__(256) void k_mv2(const float* __restrict__ y,
                                             const float* __restrict__ Wb,
                                             const float* __restrict__ bb,
                                             float* __restrict__ out) {
    __shared__ float sm[4];
    int o = blockIdx.x;
    const float4* wr = (const float4*)(Wb + (size_t)o * DH);
    const float4* yy = (const float4*)y;
    float acc = 0.0f;
#pragma unroll
    for (int it = 0; it < (DH / 4) / 256; ++it) {   // 16 iters
        int idx = it * 256 + threadIdx.x;
        float4 w = wr[idx];
        float4 x = yy[idx];
        acc += w.x * x.x + w.y * x.y + w.z * x.z + w.w * x.w;
    }
#pragma unroll
    for (int off = 32; off > 0; off >>= 1) acc += __shfl_down(acc, off, 64);
    int lane = threadIdx.x & 63, wid = threadIdx.x >> 6;
    if (lane == 0) sm[wid] = acc;
    __syncthreads();
    if (threadIdx.x == 0) out[o] = tanhf(sm[0] + sm[1] + sm[2] + sm[3] + bb[o]);
}

// ---------------------------------------------------------------------------

extern "C" void kernel_launch(void* const* d_in, const int* in_sizes, int n_in,
                              void* d_out, int out_size, void* d_ws, size_t ws_size,
                              hipStream_t stream) {
    const float* data = (const float*)d_in[0];
    const int*   edge = (const int*)d_in[1];       // [2, E] int32
    const float* W1   = (const float*)d_in[2];
    const float* b1   = (const float*)d_in[3];
    const float* W2   = (const float*)d_in[4];
    const float* b2   = (const float*)d_in[5];
    const float* W3   = (const float*)d_in[6];
    const float* b3   = (const float*)d_in[7];
    const float* Wa   = (const float*)d_in[8];
    const float* ba   = (const float*)d_in[9];
    const float* Wb   = (const float*)d_in[10];
    const float* bb   = (const float*)d_in[11];
    float* out = (float*)d_out;

    const int* src = edge;
    const int* dst = edge + NE;

    // workspace layout (floats) — everything re-initialized each call
    float* ws   = (float*)d_ws;
    float* dinv = ws;                 // [NN]       (holds deg first, then rsqrt in-place)
    float* h1   = dinv + NN;          // [NN*4]
    float* agg1 = h1 + NN * 4;        // [NN*4]
    float* h2   = agg1 + NN * 4;      // [NN*2]
    float* agg2 = h2 + NN * 2;        // [NN*2]
    float* h3   = agg2 + NN * 2;      // [NN]
    float* agg3 = h3 + NN;            // [NN]
    float* v    = agg3 + NN;          // [NN]
    float* y1   = v + NN;             // [DH]

    dim3 blk(256);
    dim3 gN((NN + 255) / 256);        // 32 blocks (node-domain)
    dim3 gE((NE + 255) / 256);        // 2048 blocks (edge-domain)

    k_deg_init<<<gN, blk, 0, stream>>>(dinv);
    k_deg_acc<<<gE, blk, 0, stream>>>(dst, dinv);
    k_dinv_h1<<<gN, blk, 0, stream>>>(data, W1, dinv, h1, agg1);
    k_scat4<<<gE, blk, 0, stream>>>(src, dst, dinv, h1, agg1);
    k_fin1_h2<<<gN, blk, 0, stream>>>(dinv, h1, agg1, b1, W2, h2, agg2);
    k_scat2<<<gE, blk, 0, stream>>>(src, dst, dinv, h2, agg2);
    k_fin2_h3<<<gN, blk, 0, stream>>>(dinv, h2, agg2, b2, W3, h3, agg3);
    k_scat1<<<gE, blk, 0, stream>>>(src, dst, dinv, h3, agg3);
    k_fin3<<<gN, blk, 0, stream>>>(dinv, h3, agg3, b3, v);
    k_mv1<<<dim3(DH), blk, 0, stream>>>(v, Wa, ba, y1);
    k_mv2<<<dim3(NOUT), blk, 0, stream>>>(y1, Wb, bb, out);
}